// Round 1
// baseline (107.381 us; speedup 1.0000x reference)
//
#include <hip/hip_runtime.h>
#include <math.h>

#define DIM 4096
#define NRF 8192
#define NBLK 1024
#define ROWS_PER_BLOCK (NRF / NBLK)            // 8
#define ROWS_PER_WAVE  (ROWS_PER_BLOCK / 4)    // 2 (4 waves/block)
#define NV4 (DIM / 4)                          // 1024 float4 per row

// ---------- Kernel A: sum of squares of x and w (f64) ----------
__global__ __launch_bounds__(256) void k_sumsq(const float* __restrict__ x,
                                               const float* __restrict__ w,
                                               double* __restrict__ out) {
    int t = threadIdx.x;
    double ax = 0.0, aw = 0.0;
    for (int i = t; i < DIM; i += 256) {
        double xv = (double)x[i];
        double wv = (double)w[i];
        ax += xv * xv;
        aw += wv * wv;
    }
    #pragma unroll
    for (int off = 32; off >= 1; off >>= 1) {
        ax += __shfl_xor(ax, off);
        aw += __shfl_xor(aw, off);
    }
    __shared__ double sx[4], sw[4];
    int wid = t >> 6;
    if ((t & 63) == 0) { sx[wid] = ax; sw[wid] = aw; }
    __syncthreads();
    if (t == 0) {
        out[0] = sx[0] + sx[1] + sx[2] + sx[3];
        out[1] = sw[0] + sw[1] + sw[2] + sw[3];
    }
}

// ---------- Kernel B: main streaming kernel ----------
// Each wave: ROWS_PER_WAVE row-pairs; per row, dot(gs_x[row],x) and
// dot(gs_w[row],w) with x,w staged in LDS. f64 accumulate; lane 0 does exp.
__global__ __launch_bounds__(256) void k_main(const float4* __restrict__ gsx,
                                              const float4* __restrict__ gsw,
                                              const float* __restrict__ xis,
                                              const float4* __restrict__ x4,
                                              const float4* __restrict__ w4,
                                              const double* __restrict__ ss,
                                              double* __restrict__ partials) {
    __shared__ float4 lx[NV4];
    __shared__ float4 lw[NV4];
    int t = threadIdx.x;
    #pragma unroll
    for (int i = 0; i < NV4 / 256; ++i) {
        lx[t + i * 256] = x4[t + i * 256];
        lw[t + i * 256] = w4[t + i * 256];
    }
    __syncthreads();

    int lane = t & 63;
    int wid  = t >> 6;
    double sxw = ss[0] + ss[1];

    double acc = 0.0;
    int row0 = blockIdx.x * ROWS_PER_BLOCK + wid * ROWS_PER_WAVE;

    for (int r = 0; r < ROWS_PER_WAVE; ++r) {
        int row = row0 + r;
        const float4* __restrict__ rx = gsx + (size_t)row * NV4;
        const float4* __restrict__ rw = gsw + (size_t)row * NV4;
        double dx = 0.0, dw = 0.0;
        #pragma unroll
        for (int k = 0; k < NV4 / 64; ++k) {       // 16 iters
            float4 a = rx[k * 64 + lane];
            float4 b = lx[k * 64 + lane];
            dx += (double)a.x * b.x + (double)a.y * b.y
                + (double)a.z * b.z + (double)a.w * b.w;
            float4 c = rw[k * 64 + lane];
            float4 d = lw[k * 64 + lane];
            dw += (double)c.x * d.x + (double)c.y * d.y
                + (double)c.z * d.z + (double)c.w * d.w;
        }
        #pragma unroll
        for (int off = 32; off >= 1; off >>= 1) {
            dx += __shfl_xor(dx, off);
            dw += __shfl_xor(dw, off);
        }
        if (lane == 0) {
            double xi = (double)xis[row];
            double e  = xi * (dx + dw) - 0.5 * xi * xi * sxw;
            acc += exp(e);
        }
    }

    __shared__ double wsum[4];
    if (lane == 0) wsum[wid] = acc;
    __syncthreads();
    if (t == 0) partials[blockIdx.x] = wsum[0] + wsum[1] + wsum[2] + wsum[3];
}

// ---------- Kernel C: final reduce ----------
__global__ __launch_bounds__(256) void k_reduce(const double* __restrict__ partials,
                                                float* __restrict__ out) {
    int t = threadIdx.x;
    double a = 0.0;
    for (int i = t; i < NBLK; i += 256) a += partials[i];
    #pragma unroll
    for (int off = 32; off >= 1; off >>= 1) a += __shfl_xor(a, off);
    __shared__ double s[4];
    if ((t & 63) == 0) s[t >> 6] = a;
    __syncthreads();
    if (t == 0) out[0] = (float)((s[0] + s[1] + s[2] + s[3]) * (1.0 / (double)NRF));
}

extern "C" void kernel_launch(void* const* d_in, const int* in_sizes, int n_in,
                              void* d_out, int out_size, void* d_ws, size_t ws_size,
                              hipStream_t stream) {
    const float* x    = (const float*)d_in[0];   // [4096]
    const float* w    = (const float*)d_in[1];   // [4096]
    const float* xis  = (const float*)d_in[2];   // [8192]
    const float4* gsx = (const float4*)d_in[3];  // [8192,4096]
    const float4* gsw = (const float4*)d_in[4];  // [8192,4096]
    float* out = (float*)d_out;

    double* ws  = (double*)d_ws;   // ws[0]=||x||^2, ws[1]=||w||^2, ws[2..2+NBLK) partials
    double* par = ws + 2;

    k_sumsq<<<1, 256, 0, stream>>>(x, w, ws);
    k_main<<<NBLK, 256, 0, stream>>>(gsx, gsw, xis,
                                     (const float4*)x, (const float4*)w,
                                     ws, par);
    k_reduce<<<1, 256, 0, stream>>>(par, out);
}

// Round 2
// 48.090 us; speedup vs baseline: 2.2329x; 2.2329x over previous
//
#include <hip/hip_runtime.h>
#include <math.h>

#define DIM 4096
#define NRF 8192
#define NBLK 1024
#define TPB  512
#define NV4  (DIM / 4)        // 1024 float4 per row
#define ROWS_PER_BLOCK 8      // 8 waves/block, 1 row-pair per wave

// ---------- Kernel: main streaming kernel ----------
// grid = 1024 blocks x 512 threads (8 waves). Each wave owns one rf index:
// dot(gs_x[row], x) and dot(gs_w[row], w) with x,w staged in LDS.
// f32 accumulate (2 accumulators per dot for ILP), sumsq fused from staged regs.
__global__ __launch_bounds__(TPB, 4) void k_main(const float4* __restrict__ gsx,
                                                 const float4* __restrict__ gsw,
                                                 const float*  __restrict__ xis,
                                                 const float4* __restrict__ x4,
                                                 const float4* __restrict__ w4,
                                                 float* __restrict__ partials) {
    __shared__ float4 lx[NV4];
    __shared__ float4 lw[NV4];
    __shared__ float  ssq_s[8];
    __shared__ float  wsum[8];

    int t = threadIdx.x;
    int lane = t & 63;
    int wid  = t >> 6;

    // Stage x, w into LDS (each thread moves 2 float4 of each).
    float4 a0 = x4[t], a1 = x4[t + TPB];
    float4 b0 = w4[t], b1 = w4[t + TPB];
    lx[t] = a0; lx[t + TPB] = a1;
    lw[t] = b0; lw[t + TPB] = b1;

    // Fused ||x||^2 + ||w||^2 from the registers we just staged.
    float ssq = a0.x*a0.x + a0.y*a0.y + a0.z*a0.z + a0.w*a0.w
              + a1.x*a1.x + a1.y*a1.y + a1.z*a1.z + a1.w*a1.w
              + b0.x*b0.x + b0.y*b0.y + b0.z*b0.z + b0.w*b0.w
              + b1.x*b1.x + b1.y*b1.y + b1.z*b1.z + b1.w*b1.w;
    #pragma unroll
    for (int off = 32; off >= 1; off >>= 1) ssq += __shfl_xor(ssq, off);
    if (lane == 0) ssq_s[wid] = ssq;
    __syncthreads();
    float sxw = ssq_s[0] + ssq_s[1] + ssq_s[2] + ssq_s[3]
              + ssq_s[4] + ssq_s[5] + ssq_s[6] + ssq_s[7];

    // One row-pair per wave.
    int row = blockIdx.x * ROWS_PER_BLOCK + wid;
    const float4* __restrict__ rx = gsx + (size_t)row * NV4;
    const float4* __restrict__ rw = gsw + (size_t)row * NV4;

    float dx0 = 0.f, dx1 = 0.f, dw0 = 0.f, dw1 = 0.f;
    #pragma unroll
    for (int k = 0; k < NV4 / 64; k += 2) {        // 16 iters, 2-way ILP
        float4 a = rx[k * 64 + lane];
        float4 b = lx[k * 64 + lane];
        dx0 += a.x*b.x + a.y*b.y + a.z*b.z + a.w*b.w;
        float4 c = rx[(k + 1) * 64 + lane];
        float4 d = lx[(k + 1) * 64 + lane];
        dx1 += c.x*d.x + c.y*d.y + c.z*d.z + c.w*d.w;
        float4 e = rw[k * 64 + lane];
        float4 f = lw[k * 64 + lane];
        dw0 += e.x*f.x + e.y*f.y + e.z*f.z + e.w*f.w;
        float4 g = rw[(k + 1) * 64 + lane];
        float4 h = lw[(k + 1) * 64 + lane];
        dw1 += g.x*h.x + g.y*h.y + g.z*h.z + g.w*h.w;
    }
    float s = (dx0 + dx1) + (dw0 + dw1);
    #pragma unroll
    for (int off = 32; off >= 1; off >>= 1) s += __shfl_xor(s, off);

    if (lane == 0) {
        float xi = xis[row];
        float e  = xi * s - 0.5f * xi * xi * sxw;
        wsum[wid] = expf(e);
    }
    __syncthreads();
    if (t == 0) {
        partials[blockIdx.x] = wsum[0] + wsum[1] + wsum[2] + wsum[3]
                             + wsum[4] + wsum[5] + wsum[6] + wsum[7];
    }
}

// ---------- Kernel: final reduce (f64 accumulate of 1024 f32 partials) ----------
__global__ __launch_bounds__(256) void k_reduce(const float* __restrict__ partials,
                                                float* __restrict__ out) {
    int t = threadIdx.x;
    double a = 0.0;
    for (int i = t; i < NBLK; i += 256) a += (double)partials[i];
    #pragma unroll
    for (int off = 32; off >= 1; off >>= 1) a += __shfl_xor(a, off);
    __shared__ double s[4];
    if ((t & 63) == 0) s[t >> 6] = a;
    __syncthreads();
    if (t == 0) out[0] = (float)((s[0] + s[1] + s[2] + s[3]) * (1.0 / (double)NRF));
}

extern "C" void kernel_launch(void* const* d_in, const int* in_sizes, int n_in,
                              void* d_out, int out_size, void* d_ws, size_t ws_size,
                              hipStream_t stream) {
    const float* x    = (const float*)d_in[0];   // [4096]
    const float* w    = (const float*)d_in[1];   // [4096]
    const float* xis  = (const float*)d_in[2];   // [8192]
    const float4* gsx = (const float4*)d_in[3];  // [8192,4096]
    const float4* gsw = (const float4*)d_in[4];  // [8192,4096]
    float* out = (float*)d_out;

    float* par = (float*)d_ws;                   // [NBLK] partials

    k_main<<<NBLK, TPB, 0, stream>>>(gsx, gsw, xis,
                                     (const float4*)x, (const float4*)w, par);
    k_reduce<<<1, 256, 0, stream>>>(par, out);
}